// Round 1
// baseline (863.317 us; speedup 1.0000x reference)
//
#include <hip/hip_runtime.h>
#include <hip/hip_bf16.h>

// Problem constants (fixed by reference setup_inputs)
constexpr int B_   = 16384;
constexpr int L_   = 10;
constexpr int E_   = 64;
constexpr int BL_  = B_ * L_;       // 163840
constexpr int K1K_ = 4 * E_;        // 256
constexpr int H1_  = 64;
constexpr int H2_  = 16;
constexpr int CF_  = 3 * E_;        // 192
constexpr int F1_  = 200;
constexpr int F2_  = 80;

// Workspace layout (in floats)
constexpr long OFF_T1    = 0;                       // BL*64 = 10485760
constexpr long OFF_SCORE = 10485760;                // BL = 163840
constexpr long OFF_CF    = 10649600;                // B*192 = 3145728
constexpr long OFF_ACC   = 13795328;                // 688 floats of accumulators
// z1/z2 alias the t1 region (t1 is dead after k_score)
constexpr long OFF_Z1    = 0;                       // B*200 = 3276800
constexpr long OFF_Z2    = 3276800;                 // B*80  = 1310720
constexpr int  ACC_N     = 688;
// acc sub-offsets: sum1 @0(64), ssq1 @64(64), sumA @128(200), ssqA @328(200),
//                  sumB @528(80), ssqB @608(80)

__device__ __forceinline__ float sigmoidf_(float x) {
    return 1.0f / (1.0f + __expf(-x));
}

__global__ __launch_bounds__(256) void k_init(float* __restrict__ acc) {
    int i = blockIdx.x * 256 + threadIdx.x;
    if (i < ACC_N) acc[i] = 0.0f;
}

// ---------------- K1: t1 = ai @ W1 + b1, plus per-feature sum/sumsq ----------
__global__ __launch_bounds__(256) void k_gemm1(
    const int* __restrict__ sparse, const int* __restrict__ seqs,
    const float* __restrict__ item_t, const float* __restrict__ his_t,
    const float* __restrict__ W1, const float* __restrict__ b1,
    float* __restrict__ t1, float* __restrict__ sum1, float* __restrict__ ssq1)
{
    __shared__ float W1s[K1K_ * H1_];   // 64 KB
    __shared__ float ais[16 * K1K_];    // 16 KB  (total 80KB -> 2 blocks/CU)
    int tid = threadIdx.x;
    for (int i = tid; i < K1K_ * H1_; i += 256) W1s[i] = W1[i];

    int jslot = tid & 15;
    int rslot = tid >> 4;
    int j0 = jslot * 4;
    float bb0 = b1[j0], bb1 = b1[j0 + 1], bb2 = b1[j0 + 2], bb3 = b1[j0 + 3];

    float ps0 = 0.f, ps1 = 0.f, ps2 = 0.f, ps3 = 0.f;
    float pq0 = 0.f, pq1 = 0.f, pq2 = 0.f, pq3 = 0.f;

    int ntile = BL_ / 16;   // 10240
    for (int tile = blockIdx.x; tile < ntile; tile += gridDim.x) {
        int row0 = tile * 16;
        __syncthreads();   // protect ais from previous iteration's readers
        // stage ai for 16 rows
        for (int i = tid; i < 16 * 64; i += 256) {
            int r = i >> 6, k = i & 63;
            int row = row0 + r;
            int b = row / L_;
            int item = sparse[2 * b + 1];
            int hidx = seqs[row];
            float q = item_t[(long)item * 64 + k];
            float h = his_t[(long)hidx * 64 + k];
            float* a = &ais[r * 256];
            a[k] = q;
            a[64 + k] = h;
            a[128 + k] = q - h;
            a[192 + k] = q * h;
        }
        __syncthreads();

        const float* arow = &ais[rslot * 256];
        float a0 = bb0, a1 = bb1, a2 = bb2, a3 = bb3;
        #pragma unroll 4
        for (int k = 0; k < 256; k += 4) {
            float4 av = *(const float4*)(arow + k);
            float4 w0 = *(const float4*)(W1s + (k + 0) * 64 + j0);
            float4 w1 = *(const float4*)(W1s + (k + 1) * 64 + j0);
            float4 w2 = *(const float4*)(W1s + (k + 2) * 64 + j0);
            float4 w3 = *(const float4*)(W1s + (k + 3) * 64 + j0);
            a0 += av.x * w0.x + av.y * w1.x + av.z * w2.x + av.w * w3.x;
            a1 += av.x * w0.y + av.y * w1.y + av.z * w2.y + av.w * w3.y;
            a2 += av.x * w0.z + av.y * w1.z + av.z * w2.z + av.w * w3.z;
            a3 += av.x * w0.w + av.y * w1.w + av.z * w2.w + av.w * w3.w;
        }
        int row = row0 + rslot;
        float4 outv; outv.x = a0; outv.y = a1; outv.z = a2; outv.w = a3;
        *(float4*)(t1 + (long)row * 64 + j0) = outv;
        ps0 += a0; ps1 += a1; ps2 += a2; ps3 += a3;
        pq0 += a0 * a0; pq1 += a1 * a1; pq2 += a2 * a2; pq3 += a3 * a3;
    }

    // block-level reduction of stats through LDS (reuse ais)
    __syncthreads();
    float* reds = ais;          // 1024 floats
    float* redq = ais + 1024;   // 1024 floats
    reds[rslot * 64 + j0 + 0] = ps0; reds[rslot * 64 + j0 + 1] = ps1;
    reds[rslot * 64 + j0 + 2] = ps2; reds[rslot * 64 + j0 + 3] = ps3;
    redq[rslot * 64 + j0 + 0] = pq0; redq[rslot * 64 + j0 + 1] = pq1;
    redq[rslot * 64 + j0 + 2] = pq2; redq[rslot * 64 + j0 + 3] = pq3;
    __syncthreads();
    if (tid < 64) {
        float s = 0.f, q = 0.f;
        #pragma unroll
        for (int r = 0; r < 16; r++) { s += reds[r * 64 + tid]; q += redq[r * 64 + tid]; }
        atomicAdd(&sum1[tid], s);
        atomicAdd(&ssq1[tid], q);
    }
}

// ---------------- K2: score = (dice3(t1) @ W2 + b2) @ Wf + bf, masked --------
__global__ __launch_bounds__(256) void k_score(
    const float* __restrict__ t1, const int* __restrict__ seqs,
    const float* __restrict__ sum1, const float* __restrict__ ssq1,
    const float* __restrict__ g1, const float* __restrict__ be1, const float* __restrict__ a1v,
    const float* __restrict__ W2, const float* __restrict__ b2,
    const float* __restrict__ Wf, const float* __restrict__ bfv,
    float* __restrict__ score)
{
    __shared__ float As[64], Bs[64], Al[64];
    __shared__ float W2s[64 * 16];
    __shared__ float Wfs[16], b2s[16];
    int tid = threadIdx.x;
    if (tid < 64) {
        float mu = sum1[tid] * (1.0f / BL_);
        float var = ssq1[tid] * (1.0f / BL_) - mu * mu;
        float rstd = rsqrtf(var + 1e-8f);
        float A = rstd * g1[tid];
        As[tid] = A;
        Bs[tid] = be1[tid] - mu * A;
        Al[tid] = a1v[tid];
    }
    for (int i = tid; i < 64 * 16; i += 256) W2s[i] = W2[i];
    if (tid < 16) { Wfs[tid] = Wf[tid]; b2s[tid] = b2[tid]; }
    __syncthreads();

    int row = blockIdx.x * 256 + tid;   // grid = 640 exact
    float h[16];
    #pragma unroll
    for (int n = 0; n < 16; n++) h[n] = b2s[n];
    const float* trow = t1 + (long)row * 64;
    #pragma unroll 4
    for (int jj = 0; jj < 64; jj += 4) {
        float4 x4 = *(const float4*)(trow + jj);
        float xs[4] = {x4.x, x4.y, x4.z, x4.w};
        #pragma unroll
        for (int u = 0; u < 4; u++) {
            int j = jj + u;
            float x = xs[u];
            float xn = x * As[j] + Bs[j];
            float p = sigmoidf_(xn);
            float al = Al[j];
            float d = x * (al + p * (1.0f - al));
            #pragma unroll
            for (int n = 0; n < 16; n++) h[n] += d * W2s[j * 16 + n];
        }
    }
    float sc = bfv[0];
    #pragma unroll
    for (int n = 0; n < 16; n++) sc += h[n] * Wfs[n];
    if (seqs[row] == 0) sc = 0.0f;
    score[row] = sc;
}

// ---------------- K2b: pooled + cf assembly ----------------------------------
__global__ __launch_bounds__(256) void k_pool(
    const int* __restrict__ sparse, const int* __restrict__ seqs,
    const float* __restrict__ user_t, const float* __restrict__ item_t,
    const float* __restrict__ his_t,
    const float* __restrict__ score, float* __restrict__ cf)
{
    int tid = threadIdx.x;
    int b = blockIdx.x * 4 + (tid >> 6);   // grid = 4096 exact
    int e = tid & 63;
    float acc = 0.0f;
    #pragma unroll
    for (int l = 0; l < L_; l++) {
        float s = score[b * L_ + l];
        int hidx = seqs[b * L_ + l];
        acc += s * his_t[(long)hidx * 64 + e];
    }
    int uidx = sparse[2 * b];
    int iidx = sparse[2 * b + 1];
    cf[(long)b * CF_ + e]        = item_t[(long)iidx * 64 + e];
    cf[(long)b * CF_ + 64 + e]   = acc;
    cf[(long)b * CF_ + 128 + e]  = user_t[(long)uidx * 64 + e];
}

// ---------------- K3: z1 = cf @ Wa + ba, plus sums ---------------------------
__global__ __launch_bounds__(256) void k_z1(
    const float* __restrict__ cf, const float* __restrict__ Wa, const float* __restrict__ ba,
    float* __restrict__ z1, float* __restrict__ sumA, float* __restrict__ ssqA)
{
    __shared__ float cfs[16 * CF_];   // 12 KB
    int tid = threadIdx.x;
    int n = tid;                      // active when n < 200
    float bav = (n < F1_) ? ba[n] : 0.0f;
    float ps = 0.f, pq = 0.f;

    int ntile = B_ / 16;   // 1024
    for (int tile = blockIdx.x; tile < ntile; tile += gridDim.x) {
        int row0 = tile * 16;
        __syncthreads();
        for (int i = tid; i < 16 * CF_; i += 256) cfs[i] = cf[(long)row0 * CF_ + i];
        __syncthreads();
        if (n < F1_) {
            float acc[16];
            #pragma unroll
            for (int r = 0; r < 16; r++) acc[r] = 0.0f;
            for (int k = 0; k < CF_; k += 4) {
                float w0 = Wa[(long)(k + 0) * F1_ + n];
                float w1 = Wa[(long)(k + 1) * F1_ + n];
                float w2 = Wa[(long)(k + 2) * F1_ + n];
                float w3 = Wa[(long)(k + 3) * F1_ + n];
                #pragma unroll
                for (int r = 0; r < 16; r++) {
                    float4 c4 = *(const float4*)&cfs[r * CF_ + k];
                    acc[r] += c4.x * w0 + c4.y * w1 + c4.z * w2 + c4.w * w3;
                }
            }
            #pragma unroll
            for (int r = 0; r < 16; r++) {
                float v = acc[r] + bav;
                z1[(long)(row0 + r) * F1_ + n] = v;
                ps += v; pq += v * v;
            }
        }
    }
    if (n < F1_) {
        atomicAdd(&sumA[n], ps);
        atomicAdd(&ssqA[n], pq);
    }
}

// ---------------- K4: z2 = dice2(z1) @ Wb + bb, plus sums --------------------
__global__ __launch_bounds__(320) void k_z2(
    const float* __restrict__ z1, const float* __restrict__ Wb, const float* __restrict__ bbv,
    const float* __restrict__ sumA, const float* __restrict__ ssqA,
    const float* __restrict__ ga, const float* __restrict__ bea, const float* __restrict__ aav,
    float* __restrict__ z2, float* __restrict__ sumB, float* __restrict__ ssqB)
{
    __shared__ float zs[16 * F1_];    // 12.8 KB
    __shared__ float Aa[F1_], Ba[F1_], ala[F1_];
    int tid = threadIdx.x;
    if (tid < F1_) {
        float mu = sumA[tid] * (1.0f / B_);
        float var = ssqA[tid] * (1.0f / B_) - mu * mu;
        float rstd = rsqrtf(var + 1e-8f);
        float A = rstd * ga[tid];
        Aa[tid] = A;
        Ba[tid] = bea[tid] - mu * A;
        ala[tid] = aav[tid];
    }
    int n = tid % F2_;       // 0..79
    int rgrp = tid / F2_;    // 0..3
    float bbl = bbv[n];
    float ps = 0.f, pq = 0.f;

    int ntile = B_ / 16;   // 1024
    for (int tile = blockIdx.x; tile < ntile; tile += gridDim.x) {
        int row0 = tile * 16;
        __syncthreads();
        for (int i = tid; i < 16 * F1_; i += 320) {
            int k = i % F1_;
            float x = z1[(long)row0 * F1_ + i];
            float xn = x * Aa[k] + Ba[k];
            float p = sigmoidf_(xn);
            float al = ala[k];
            zs[i] = x * (al + p * (1.0f - al));
        }
        __syncthreads();
        float acc[4] = {0.f, 0.f, 0.f, 0.f};
        for (int k = 0; k < F1_; k += 4) {
            float w0 = Wb[(long)(k + 0) * F2_ + n];
            float w1 = Wb[(long)(k + 1) * F2_ + n];
            float w2 = Wb[(long)(k + 2) * F2_ + n];
            float w3 = Wb[(long)(k + 3) * F2_ + n];
            #pragma unroll
            for (int rr = 0; rr < 4; rr++) {
                float4 c4 = *(const float4*)&zs[(rgrp * 4 + rr) * F1_ + k];
                acc[rr] += c4.x * w0 + c4.y * w1 + c4.z * w2 + c4.w * w3;
            }
        }
        #pragma unroll
        for (int rr = 0; rr < 4; rr++) {
            int row = row0 + rgrp * 4 + rr;
            float v = acc[rr] + bbl;
            z2[(long)row * F2_ + n] = v;
            ps += v; pq += v * v;
        }
    }
    atomicAdd(&sumB[n], ps);
    atomicAdd(&ssqB[n], pq);
}

// ---------------- K5: out = sigmoid(dice2(z2) @ Wc + bc) ---------------------
__global__ __launch_bounds__(256) void k_out(
    const float* __restrict__ z2,
    const float* __restrict__ sumB, const float* __restrict__ ssqB,
    const float* __restrict__ gb, const float* __restrict__ beb, const float* __restrict__ abv,
    const float* __restrict__ Wc, const float* __restrict__ bc,
    float* __restrict__ out)
{
    __shared__ float Ab[F2_], Bb[F2_], alb[F2_], Wcs[F2_];
    int tid = threadIdx.x;
    if (tid < F2_) {
        float mu = sumB[tid] * (1.0f / B_);
        float var = ssqB[tid] * (1.0f / B_) - mu * mu;
        float rstd = rsqrtf(var + 1e-8f);
        float A = rstd * gb[tid];
        Ab[tid] = A;
        Bb[tid] = beb[tid] - mu * A;
        alb[tid] = abv[tid];
        Wcs[tid] = Wc[tid];
    }
    __syncthreads();
    int row = blockIdx.x * 256 + tid;   // grid = 64 exact
    const float* zrow = z2 + (long)row * F2_;
    float acc = bc[0];
    #pragma unroll 4
    for (int k = 0; k < F2_; k += 4) {
        float4 x4 = *(const float4*)(zrow + k);
        float xs[4] = {x4.x, x4.y, x4.z, x4.w};
        #pragma unroll
        for (int u = 0; u < 4; u++) {
            int kk = k + u;
            float x = xs[u];
            float xn = x * Ab[kk] + Bb[kk];
            float p = sigmoidf_(xn);
            float al = alb[kk];
            float d = x * (al + p * (1.0f - al));
            acc += d * Wcs[kk];
        }
    }
    out[row] = sigmoidf_(acc);
}

extern "C" void kernel_launch(void* const* d_in, const int* in_sizes, int n_in,
                              void* d_out, int out_size, void* d_ws, size_t ws_size,
                              hipStream_t stream) {
    const int*   sparse = (const int*)  d_in[0];
    const int*   seqs   = (const int*)  d_in[1];
    const float* user_t = (const float*)d_in[2];
    const float* item_t = (const float*)d_in[3];
    const float* his_t  = (const float*)d_in[4];
    const float* W1  = (const float*)d_in[5];
    const float* b1  = (const float*)d_in[6];
    const float* g1  = (const float*)d_in[7];
    const float* be1 = (const float*)d_in[8];
    const float* a1  = (const float*)d_in[9];
    const float* W2  = (const float*)d_in[10];
    const float* b2  = (const float*)d_in[11];
    const float* Wf  = (const float*)d_in[12];
    const float* bfv = (const float*)d_in[13];
    const float* Wa  = (const float*)d_in[14];
    const float* ba  = (const float*)d_in[15];
    const float* ga  = (const float*)d_in[16];
    const float* bea = (const float*)d_in[17];
    const float* aa  = (const float*)d_in[18];
    const float* Wb  = (const float*)d_in[19];
    const float* bb  = (const float*)d_in[20];
    const float* gb  = (const float*)d_in[21];
    const float* beb = (const float*)d_in[22];
    const float* ab  = (const float*)d_in[23];
    const float* Wc  = (const float*)d_in[24];
    const float* bc  = (const float*)d_in[25];

    float* ws    = (float*)d_ws;
    float* t1    = ws + OFF_T1;
    float* score = ws + OFF_SCORE;
    float* cf    = ws + OFF_CF;
    float* acc   = ws + OFF_ACC;
    float* sum1  = acc;
    float* ssq1  = acc + 64;
    float* sumA  = acc + 128;
    float* ssqA  = acc + 328;
    float* sumB  = acc + 528;
    float* ssqB  = acc + 608;
    float* z1    = ws + OFF_Z1;
    float* z2    = ws + OFF_Z2;
    float* out   = (float*)d_out;

    k_init<<<3, 256, 0, stream>>>(acc);
    k_gemm1<<<512, 256, 0, stream>>>(sparse, seqs, item_t, his_t, W1, b1, t1, sum1, ssq1);
    k_score<<<BL_ / 256, 256, 0, stream>>>(t1, seqs, sum1, ssq1, g1, be1, a1, W2, b2, Wf, bfv, score);
    k_pool<<<B_ / 4, 256, 0, stream>>>(sparse, seqs, user_t, item_t, his_t, score, cf);
    k_z1<<<512, 256, 0, stream>>>(cf, Wa, ba, z1, sumA, ssqA);
    k_z2<<<512, 320, 0, stream>>>(z1, Wb, bb, sumA, ssqA, ga, bea, aa, z2, sumB, ssqB);
    k_out<<<B_ / 256, 256, 0, stream>>>(z2, sumB, ssqB, gb, beb, ab, Wc, bc, out);
}

// Round 2
// 745.707 us; speedup vs baseline: 1.1577x; 1.1577x over previous
//
#include <hip/hip_runtime.h>
#include <hip/hip_bf16.h>

// Problem constants (fixed by reference setup_inputs)
constexpr int B_   = 16384;
constexpr int L_   = 10;
constexpr int E_   = 64;
constexpr int BL_  = B_ * L_;       // 163840
constexpr int H1_  = 64;
constexpr int H2_  = 16;
constexpr int CF_  = 3 * E_;        // 192
constexpr int F1_  = 200;
constexpr int F2_  = 80;

// Workspace layout (in floats)
constexpr long OFF_T1    = 0;                       // BL*64 = 10485760
constexpr long OFF_SCORE = 10485760;                // BL = 163840 (also aliases W1t bf16 during k_gemm1)
constexpr long OFF_CF    = 10649600;                // B*192 = 3145728
constexpr long OFF_ACC   = 13795328;                // 688 floats of accumulators
constexpr long OFF_Z1    = 0;                       // B*200 (aliases dead t1)
constexpr long OFF_Z2    = 3276800;                 // B*80
constexpr int  ACC_N     = 688;

typedef __bf16 bf16x8 __attribute__((ext_vector_type(8)));
typedef float  f32x4  __attribute__((ext_vector_type(4)));

__device__ __forceinline__ float sigmoidf_(float x) {
    return 1.0f / (1.0f + __expf(-x));
}

__device__ __forceinline__ unsigned short f2bf(float f) {
    unsigned u = __float_as_uint(f);
    unsigned r = (u + 0x7fffu + ((u >> 16) & 1u)) >> 16;   // RNE, values are finite
    return (unsigned short)r;
}
__device__ __forceinline__ unsigned pk2(float a, float b) {
    return (unsigned)f2bf(a) | ((unsigned)f2bf(b) << 16);
}

// ---------------- K0: zero accumulators + build W1t (bf16, transposed) -------
__global__ __launch_bounds__(256) void k_init(
    float* __restrict__ acc, const float* __restrict__ W1,
    unsigned short* __restrict__ W1t)
{
    int i = blockIdx.x * 256 + threadIdx.x;   // grid 64 -> i < 16384
    if (i < ACC_N) acc[i] = 0.0f;
    // W1 is [K=256][N=64] row-major f32; W1t is [N=64][K=256] bf16
    int k = i >> 6, n = i & 63;               // coalesced read of W1
    W1t[n * 256 + k] = f2bf(W1[i]);
}

// ---------------- K1: t1 = ai @ W1 + b1 via bf16 MFMA, plus stats ------------
// Tile: 64 rows x 64 cols per block (4 waves). Wave w owns cols [16w,16w+16),
// keeps its whole B-operand (W1t) in 32 VGPRs. A staged in LDS, padded rows.
constexpr int AROW = 132;   // uints per A row: 256 bf16 = 128 dwords, +4 dword pad
__global__ __launch_bounds__(256) void k_gemm1(
    const int* __restrict__ sparse, const int* __restrict__ seqs,
    const float* __restrict__ item_t, const float* __restrict__ his_t,
    const unsigned short* __restrict__ W1t, const float* __restrict__ b1,
    float* __restrict__ t1, float* __restrict__ sum1, float* __restrict__ ssq1)
{
    __shared__ unsigned As[64 * AROW];        // 33 KB
    __shared__ float redS[4][64];
    __shared__ float redQ[4][64];

    int tid  = threadIdx.x;
    int lane = tid & 63;
    int wave = tid >> 6;
    int m    = lane & 15;
    int quad = (lane >> 4) & 3;
    int colg = 16 * wave + m;                 // this lane's output column

    // B fragments: b_frag[kk][j] = B[kk*32 + quad*8 + j][n = colg] = W1t[colg][...]
    bf16x8 bfr[8];
    {
        const unsigned short* wp = W1t + (long)colg * 256 + quad * 8;
        #pragma unroll
        for (int kk = 0; kk < 8; kk++)
            bfr[kk] = *(const bf16x8*)(wp + kk * 32);
    }
    float bias = b1[colg];
    float ps = 0.0f, pq = 0.0f;

    for (int tile = blockIdx.x; tile < BL_ / 64; tile += gridDim.x) {
        int row0 = tile * 64;
        __syncthreads();                      // As readers from prev tile done
        // stage ai tile: 64 rows x 32 bf16-pairs, 4 segments (q,h,q-h,q*h)
        #pragma unroll
        for (int t = 0; t < 8; t++) {
            int slot = t * 256 + tid;         // 0..2047
            int p = slot & 31;                // pair index (cols 2p,2p+1)
            int r = slot >> 5;                // row within tile
            int row = row0 + r;
            int b = (unsigned)row / 10u;
            int item = sparse[2 * b + 1];
            int hidx = seqs[row];
            float2 q2 = *(const float2*)(item_t + (long)item * 64 + 2 * p);
            float2 h2 = *(const float2*)(his_t  + (long)hidx * 64 + 2 * p);
            unsigned* a = &As[r * AROW];
            a[p]      = pk2(q2.x, q2.y);
            a[32 + p] = pk2(h2.x, h2.y);
            a[64 + p] = pk2(q2.x - h2.x, q2.y - h2.y);
            a[96 + p] = pk2(q2.x * h2.x, q2.y * h2.y);
        }
        __syncthreads();

        f32x4 acc[4] = {{0,0,0,0},{0,0,0,0},{0,0,0,0},{0,0,0,0}};
        #pragma unroll
        for (int kk = 0; kk < 8; kk++) {
            int aoff = kk * 16 + quad * 4;    // dword offset for k = kk*32 + quad*8
            bf16x8 a0 = *(const bf16x8*)&As[( 0 + m) * AROW + aoff];
            bf16x8 a1 = *(const bf16x8*)&As[(16 + m) * AROW + aoff];
            bf16x8 a2 = *(const bf16x8*)&As[(32 + m) * AROW + aoff];
            bf16x8 a3 = *(const bf16x8*)&As[(48 + m) * AROW + aoff];
            acc[0] = __builtin_amdgcn_mfma_f32_16x16x32_bf16(a0, bfr[kk], acc[0], 0, 0, 0);
            acc[1] = __builtin_amdgcn_mfma_f32_16x16x32_bf16(a1, bfr[kk], acc[1], 0, 0, 0);
            acc[2] = __builtin_amdgcn_mfma_f32_16x16x32_bf16(a2, bfr[kk], acc[2], 0, 0, 0);
            acc[3] = __builtin_amdgcn_mfma_f32_16x16x32_bf16(a3, bfr[kk], acc[3], 0, 0, 0);
        }
        // epilogue: D row = 16*rs + quad*4 + reg, col = colg
        float* tb = t1 + (long)row0 * 64 + colg;
        #pragma unroll
        for (int rs = 0; rs < 4; rs++) {
            #pragma unroll
            for (int reg = 0; reg < 4; reg++) {
                float v = acc[rs][reg] + bias;
                tb[(16 * rs + quad * 4 + reg) * 64] = v;
                ps += v; pq += v * v;
            }
        }
    }

    __syncthreads();
    redS[quad][colg] = ps;
    redQ[quad][colg] = pq;
    __syncthreads();
    if (tid < 64) {
        float s = redS[0][tid] + redS[1][tid] + redS[2][tid] + redS[3][tid];
        float q = redQ[0][tid] + redQ[1][tid] + redQ[2][tid] + redQ[3][tid];
        atomicAdd(&sum1[tid], s);
        atomicAdd(&ssq1[tid], q);
    }
}

// ---------------- K2: score = (dice3(t1) @ W2 + b2) @ Wf + bf, masked --------
__global__ __launch_bounds__(256) void k_score(
    const float* __restrict__ t1, const int* __restrict__ seqs,
    const float* __restrict__ sum1, const float* __restrict__ ssq1,
    const float* __restrict__ g1, const float* __restrict__ be1, const float* __restrict__ a1v,
    const float* __restrict__ W2, const float* __restrict__ b2,
    const float* __restrict__ Wf, const float* __restrict__ bfv,
    float* __restrict__ score)
{
    __shared__ float As[64], Bs[64], Al[64];
    __shared__ float W2s[64 * 16];
    __shared__ float Wfs[16], b2s[16];
    int tid = threadIdx.x;
    if (tid < 64) {
        float mu = sum1[tid] * (1.0f / BL_);
        float var = ssq1[tid] * (1.0f / BL_) - mu * mu;
        float rstd = rsqrtf(var + 1e-8f);
        float A = rstd * g1[tid];
        As[tid] = A;
        Bs[tid] = be1[tid] - mu * A;
        Al[tid] = a1v[tid];
    }
    for (int i = tid; i < 64 * 16; i += 256) W2s[i] = W2[i];
    if (tid < 16) { Wfs[tid] = Wf[tid]; b2s[tid] = b2[tid]; }
    __syncthreads();

    int row = blockIdx.x * 256 + tid;   // grid = 640 exact
    float h[16];
    #pragma unroll
    for (int n = 0; n < 16; n++) h[n] = b2s[n];
    const float* trow = t1 + (long)row * 64;
    #pragma unroll 4
    for (int jj = 0; jj < 64; jj += 4) {
        float4 x4 = *(const float4*)(trow + jj);
        float xs[4] = {x4.x, x4.y, x4.z, x4.w};
        #pragma unroll
        for (int u = 0; u < 4; u++) {
            int j = jj + u;
            float x = xs[u];
            float xn = x * As[j] + Bs[j];
            float p = sigmoidf_(xn);
            float al = Al[j];
            float d = x * (al + p * (1.0f - al));
            #pragma unroll
            for (int n = 0; n < 16; n++) h[n] += d * W2s[j * 16 + n];
        }
    }
    float sc = bfv[0];
    #pragma unroll
    for (int n = 0; n < 16; n++) sc += h[n] * Wfs[n];
    if (seqs[row] == 0) sc = 0.0f;
    score[row] = sc;
}

// ---------------- K2b: pooled + cf assembly ----------------------------------
__global__ __launch_bounds__(256) void k_pool(
    const int* __restrict__ sparse, const int* __restrict__ seqs,
    const float* __restrict__ user_t, const float* __restrict__ item_t,
    const float* __restrict__ his_t,
    const float* __restrict__ score, float* __restrict__ cf)
{
    int tid = threadIdx.x;
    int b = blockIdx.x * 4 + (tid >> 6);   // grid = 4096 exact
    int e = tid & 63;
    float acc = 0.0f;
    #pragma unroll
    for (int l = 0; l < L_; l++) {
        float s = score[b * L_ + l];
        int hidx = seqs[b * L_ + l];
        acc += s * his_t[(long)hidx * 64 + e];
    }
    int uidx = sparse[2 * b];
    int iidx = sparse[2 * b + 1];
    cf[(long)b * CF_ + e]        = item_t[(long)iidx * 64 + e];
    cf[(long)b * CF_ + 64 + e]   = acc;
    cf[(long)b * CF_ + 128 + e]  = user_t[(long)uidx * 64 + e];
}

// ---------------- K3: z1 = cf @ Wa + ba, plus sums ---------------------------
__global__ __launch_bounds__(256) void k_z1(
    const float* __restrict__ cf, const float* __restrict__ Wa, const float* __restrict__ ba,
    float* __restrict__ z1, float* __restrict__ sumA, float* __restrict__ ssqA)
{
    __shared__ float cfs[16 * CF_];   // 12 KB
    int tid = threadIdx.x;
    int n = tid;                      // active when n < 200
    float bav = (n < F1_) ? ba[n] : 0.0f;
    float ps = 0.f, pq = 0.f;

    int ntile = B_ / 16;   // 1024
    for (int tile = blockIdx.x; tile < ntile; tile += gridDim.x) {
        int row0 = tile * 16;
        __syncthreads();
        for (int i = tid; i < 16 * CF_; i += 256) cfs[i] = cf[(long)row0 * CF_ + i];
        __syncthreads();
        if (n < F1_) {
            float acc[16];
            #pragma unroll
            for (int r = 0; r < 16; r++) acc[r] = 0.0f;
            for (int k = 0; k < CF_; k += 4) {
                float w0 = Wa[(long)(k + 0) * F1_ + n];
                float w1 = Wa[(long)(k + 1) * F1_ + n];
                float w2 = Wa[(long)(k + 2) * F1_ + n];
                float w3 = Wa[(long)(k + 3) * F1_ + n];
                #pragma unroll
                for (int r = 0; r < 16; r++) {
                    float4 c4 = *(const float4*)&cfs[r * CF_ + k];
                    acc[r] += c4.x * w0 + c4.y * w1 + c4.z * w2 + c4.w * w3;
                }
            }
            #pragma unroll
            for (int r = 0; r < 16; r++) {
                float v = acc[r] + bav;
                z1[(long)(row0 + r) * F1_ + n] = v;
                ps += v; pq += v * v;
            }
        }
    }
    if (n < F1_) {
        atomicAdd(&sumA[n], ps);
        atomicAdd(&ssqA[n], pq);
    }
}

// ---------------- K4: z2 = dice2(z1) @ Wb + bb, plus sums --------------------
__global__ __launch_bounds__(320) void k_z2(
    const float* __restrict__ z1, const float* __restrict__ Wb, const float* __restrict__ bbv,
    const float* __restrict__ sumA, const float* __restrict__ ssqA,
    const float* __restrict__ ga, const float* __restrict__ bea, const float* __restrict__ aav,
    float* __restrict__ z2, float* __restrict__ sumB, float* __restrict__ ssqB)
{
    __shared__ float zs[16 * F1_];    // 12.8 KB
    __shared__ float Aa[F1_], Ba[F1_], ala[F1_];
    int tid = threadIdx.x;
    if (tid < F1_) {
        float mu = sumA[tid] * (1.0f / B_);
        float var = ssqA[tid] * (1.0f / B_) - mu * mu;
        float rstd = rsqrtf(var + 1e-8f);
        float A = rstd * ga[tid];
        Aa[tid] = A;
        Ba[tid] = bea[tid] - mu * A;
        ala[tid] = aav[tid];
    }
    int n = tid % F2_;       // 0..79
    int rgrp = tid / F2_;    // 0..3
    float bbl = bbv[n];
    float ps = 0.f, pq = 0.f;

    int ntile = B_ / 16;   // 1024
    for (int tile = blockIdx.x; tile < ntile; tile += gridDim.x) {
        int row0 = tile * 16;
        __syncthreads();
        for (int i = tid; i < 16 * F1_; i += 320) {
            int k = i % F1_;
            float x = z1[(long)row0 * F1_ + i];
            float xn = x * Aa[k] + Ba[k];
            float p = sigmoidf_(xn);
            float al = ala[k];
            zs[i] = x * (al + p * (1.0f - al));
        }
        __syncthreads();
        float acc[4] = {0.f, 0.f, 0.f, 0.f};
        for (int k = 0; k < F1_; k += 4) {
            float w0 = Wb[(long)(k + 0) * F2_ + n];
            float w1 = Wb[(long)(k + 1) * F2_ + n];
            float w2 = Wb[(long)(k + 2) * F2_ + n];
            float w3 = Wb[(long)(k + 3) * F2_ + n];
            #pragma unroll
            for (int rr = 0; rr < 4; rr++) {
                float4 c4 = *(const float4*)&zs[(rgrp * 4 + rr) * F1_ + k];
                acc[rr] += c4.x * w0 + c4.y * w1 + c4.z * w2 + c4.w * w3;
            }
        }
        #pragma unroll
        for (int rr = 0; rr < 4; rr++) {
            int row = row0 + rgrp * 4 + rr;
            float v = acc[rr] + bbl;
            z2[(long)row * F2_ + n] = v;
            ps += v; pq += v * v;
        }
    }
    atomicAdd(&sumB[n], ps);
    atomicAdd(&ssqB[n], pq);
}

// ---------------- K5: out = sigmoid(dice2(z2) @ Wc + bc) ---------------------
__global__ __launch_bounds__(256) void k_out(
    const float* __restrict__ z2,
    const float* __restrict__ sumB, const float* __restrict__ ssqB,
    const float* __restrict__ gb, const float* __restrict__ beb, const float* __restrict__ abv,
    const float* __restrict__ Wc, const float* __restrict__ bc,
    float* __restrict__ out)
{
    __shared__ float Ab[F2_], Bb[F2_], alb[F2_], Wcs[F2_];
    int tid = threadIdx.x;
    if (tid < F2_) {
        float mu = sumB[tid] * (1.0f / B_);
        float var = ssqB[tid] * (1.0f / B_) - mu * mu;
        float rstd = rsqrtf(var + 1e-8f);
        float A = rstd * gb[tid];
        Ab[tid] = A;
        Bb[tid] = beb[tid] - mu * A;
        alb[tid] = abv[tid];
        Wcs[tid] = Wc[tid];
    }
    __syncthreads();
    int row = blockIdx.x * 256 + tid;   // grid = 64 exact
    const float* zrow = z2 + (long)row * F2_;
    float acc = bc[0];
    #pragma unroll 4
    for (int k = 0; k < F2_; k += 4) {
        float4 x4 = *(const float4*)(zrow + k);
        float xs[4] = {x4.x, x4.y, x4.z, x4.w};
        #pragma unroll
        for (int u = 0; u < 4; u++) {
            int kk = k + u;
            float x = xs[u];
            float xn = x * Ab[kk] + Bb[kk];
            float p = sigmoidf_(xn);
            float al = alb[kk];
            float d = x * (al + p * (1.0f - al));
            acc += d * Wcs[kk];
        }
    }
    out[row] = sigmoidf_(acc);
}

extern "C" void kernel_launch(void* const* d_in, const int* in_sizes, int n_in,
                              void* d_out, int out_size, void* d_ws, size_t ws_size,
                              hipStream_t stream) {
    const int*   sparse = (const int*)  d_in[0];
    const int*   seqs   = (const int*)  d_in[1];
    const float* user_t = (const float*)d_in[2];
    const float* item_t = (const float*)d_in[3];
    const float* his_t  = (const float*)d_in[4];
    const float* W1  = (const float*)d_in[5];
    const float* b1  = (const float*)d_in[6];
    const float* g1  = (const float*)d_in[7];
    const float* be1 = (const float*)d_in[8];
    const float* a1  = (const float*)d_in[9];
    const float* W2  = (const float*)d_in[10];
    const float* b2  = (const float*)d_in[11];
    const float* Wf  = (const float*)d_in[12];
    const float* bfv = (const float*)d_in[13];
    const float* Wa  = (const float*)d_in[14];
    const float* ba  = (const float*)d_in[15];
    const float* ga  = (const float*)d_in[16];
    const float* bea = (const float*)d_in[17];
    const float* aa  = (const float*)d_in[18];
    const float* Wb  = (const float*)d_in[19];
    const float* bb  = (const float*)d_in[20];
    const float* gb  = (const float*)d_in[21];
    const float* beb = (const float*)d_in[22];
    const float* ab  = (const float*)d_in[23];
    const float* Wc  = (const float*)d_in[24];
    const float* bc  = (const float*)d_in[25];

    float* ws    = (float*)d_ws;
    float* t1    = ws + OFF_T1;
    float* score = ws + OFF_SCORE;
    float* cf    = ws + OFF_CF;
    float* acc   = ws + OFF_ACC;
    float* sum1  = acc;
    float* ssq1  = acc + 64;
    float* sumA  = acc + 128;
    float* ssqA  = acc + 328;
    float* sumB  = acc + 528;
    float* ssqB  = acc + 608;
    float* z1    = ws + OFF_Z1;
    float* z2    = ws + OFF_Z2;
    float* out   = (float*)d_out;
    // W1t (bf16 64x256 = 32 KB) aliases the score region: dead before k_score writes it
    unsigned short* W1t = (unsigned short*)(ws + OFF_SCORE);

    k_init<<<64, 256, 0, stream>>>(acc, W1, W1t);
    k_gemm1<<<1024, 256, 0, stream>>>(sparse, seqs, item_t, his_t, W1t, b1, t1, sum1, ssq1);
    k_score<<<BL_ / 256, 256, 0, stream>>>(t1, seqs, sum1, ssq1, g1, be1, a1, W2, b2, Wf, bfv, score);
    k_pool<<<B_ / 4, 256, 0, stream>>>(sparse, seqs, user_t, item_t, his_t, score, cf);
    k_z1<<<512, 256, 0, stream>>>(cf, Wa, ba, z1, sumA, ssqA);
    k_z2<<<512, 320, 0, stream>>>(z1, Wb, bb, sumA, ssqA, ga, bea, aa, z2, sumB, ssqB);
    k_out<<<B_ / 256, 256, 0, stream>>>(z2, sumB, ssqB, gb, beb, ab, Wc, bc, out);
}